// Round 1
// baseline (311.156 us; speedup 1.0000x reference)
//
#include <hip/hip_runtime.h>
#include <hip/hip_bf16.h>
#include <math.h>

#define B_ 2
#define T_ 2048
#define C_ 1024
#define NH_ 16
#define HS_ 64
#define BD_ 16
#define DELTA 64

typedef __attribute__((ext_vector_type(8))) short bf16x8_t;
typedef __attribute__((ext_vector_type(4))) float f32x4_t;

__device__ __forceinline__ unsigned short f2bf(float f) {
    unsigned u = __float_as_uint(f);
    u = u + 0x7fffu + ((u >> 16) & 1u);
    return (unsigned short)(u >> 16);
}
__device__ __forceinline__ float bf2f(unsigned short h) {
    return __uint_as_float(((unsigned)h) << 16);
}

// ---- prep: fp32 -> bf16 conversion for x, W_val, c_proj_w ----
__global__ __launch_bounds__(256) void cvt_kernel(
    const float* __restrict__ x, const float* __restrict__ wval,
    const float* __restrict__ cproj,
    unsigned short* __restrict__ xb, unsigned short* __restrict__ wvalb,
    unsigned short* __restrict__ cprojb)
{
    const long long NX = (long long)B_*T_*C_;   // 4194304
    const long long NW = (long long)C_*C_;      // 1048576
    long long e = ((long long)blockIdx.x * 256 + threadIdx.x) * 4;
    const float* src; unsigned short* dst; long long off;
    if (e < NX)            { src = x;     dst = xb;     off = e; }
    else if (e < NX + NW)  { src = wval;  dst = wvalb;  off = e - NX; }
    else                   { src = cproj; dst = cprojb; off = e - NX - NW; }
    float4 v = *(const float4*)(src + off);
    ushort4 o;
    o.x = f2bf(v.x); o.y = f2bf(v.y); o.z = f2bf(v.z); o.w = f2bf(v.w);
    *(ushort4*)(dst + off) = o;
}

// ---- W_comb[h*32+j, c] = sum_d sfw[j*16+d] * W_disp[(h*16+d)*1024 + c] ----
__global__ __launch_bounds__(256) void wcomb_kernel(
    const float* __restrict__ Wd, const float* __restrict__ sfw,
    unsigned short* __restrict__ wc)
{
    int idx = blockIdx.x * 256 + threadIdx.x;   // 512*1024 = 524288 total
    int c = idx & 1023, row = idx >> 10;        // row = h*32 + j
    int h = row >> 5, j = row & 31;
    float s = 0.f;
    #pragma unroll
    for (int d = 0; d < 16; ++d) s += sfw[j*16 + d] * Wd[(h*16 + d)*1024 + c];
    wc[idx] = f2bf(s);
}

// ---- pos_feat[w, j] = sum_d rel[w*16+d] * ppw[j*16+d] ----
__global__ __launch_bounds__(256) void posfeat_kernel(
    const float* __restrict__ rel, const float* __restrict__ ppw,
    float* __restrict__ pf)
{
    int idx = blockIdx.x * 256 + threadIdx.x;
    if (idx >= 64*16) return;
    int w_ = idx >> 4, j = idx & 15;
    float s = 0.f;
    #pragma unroll
    for (int d = 0; d < 16; ++d) s += rel[w_*16 + d] * ppw[j*16 + d];
    pf[idx] = s;
}

// ---- C[M,N] = A[M,K] @ Bw[N,K]^T, bf16 inputs, fp32 accumulate ----
// 64x64 tile, BK=32, 4 waves in 2x2, each wave 32x32 via 2x2 mfma_16x16x32.
template<int OUT_BF16>
__global__ __launch_bounds__(256) void gemm_bt(
    const unsigned short* __restrict__ A,
    const unsigned short* __restrict__ Bw,
    void* __restrict__ Cp, int M, int N, int K)
{
    __shared__ unsigned short As[64*40];   // pad 32 -> 40 to spread banks
    __shared__ unsigned short Bs[64*40];
    const int tid = threadIdx.x;
    const int lane = tid & 63;
    const int wid = tid >> 6;
    const int waveM = wid >> 1, waveN = wid & 1;
    const int m0 = blockIdx.y * 64, n0 = blockIdx.x * 64;
    const int r = tid >> 2, cs = tid & 3;
    const int row16 = lane & 15, quad = lane >> 4;

    f32x4_t acc[2][2];
    #pragma unroll
    for (int i = 0; i < 2; ++i)
        #pragma unroll
        for (int j = 0; j < 2; ++j) { f32x4_t z = {0.f,0.f,0.f,0.f}; acc[i][j] = z; }

    for (int k0 = 0; k0 < K; k0 += 32) {
        uint4 av = *(const uint4*)(A  + (long long)(m0 + r) * K + k0 + cs*8);
        uint4 bv = *(const uint4*)(Bw + (long long)(n0 + r) * K + k0 + cs*8);
        __syncthreads();
        *(uint4*)(As + r*40 + cs*8) = av;
        *(uint4*)(Bs + r*40 + cs*8) = bv;
        __syncthreads();
        bf16x8_t af[2], bfv[2];
        #pragma unroll
        for (int mt = 0; mt < 2; ++mt)
            af[mt] = *(const bf16x8_t*)(As + (waveM*32 + mt*16 + row16)*40 + quad*8);
        #pragma unroll
        for (int nt = 0; nt < 2; ++nt)
            bfv[nt] = *(const bf16x8_t*)(Bs + (waveN*32 + nt*16 + row16)*40 + quad*8);
        #pragma unroll
        for (int mt = 0; mt < 2; ++mt)
            #pragma unroll
            for (int nt = 0; nt < 2; ++nt)
                acc[mt][nt] = __builtin_amdgcn_mfma_f32_16x16x32_bf16(
                    af[mt], bfv[nt], acc[mt][nt], 0, 0, 0);
    }
    // C/D layout: col = lane&15, row = (lane>>4)*4 + reg   [m89/m91 verified]
    #pragma unroll
    for (int mt = 0; mt < 2; ++mt)
        #pragma unroll
        for (int nt = 0; nt < 2; ++nt) {
            int col = n0 + waveN*32 + nt*16 + row16;
            #pragma unroll
            for (int rr = 0; rr < 4; ++rr) {
                int row = m0 + waveM*32 + mt*16 + quad*4 + rr;
                float v = acc[mt][nt][rr];
                if (OUT_BF16)
                    ((unsigned short*)Cp)[(long long)row * N + col] = f2bf(v);
                else
                    ((float*)Cp)[(long long)row * N + col] = v;
            }
        }
}

// ---- windowed attention: one block per (b, h, 64 t's); one wave per t ----
__global__ __launch_bounds__(256) void attn_kernel(
    const float* __restrict__ proj,           // (B*T, 512): [.., h*32+j]
    const unsigned short* __restrict__ valb,  // (B*T, 1024): [.., h*64+d]
    const float* __restrict__ posf,           // (64,16)
    const float* __restrict__ sfb,            // (32,)
    const float* __restrict__ bw,             // (16,)
    const float* __restrict__ dw,             // (16,)
    const float* __restrict__ db,             // (1,)
    unsigned short* __restrict__ attb)        // (B*T, 1024)
{
    __shared__ float projL[127*33];           // rows s in [t0-63, t0+63], pad 33
    __shared__ unsigned short valL[127*64];
    __shared__ float posL[64*17];
    const int t0 = blockIdx.x * 64;
    const int h = blockIdx.y, b = blockIdx.z;
    const int tid = threadIdx.x;

    for (int e = tid; e < 127*32; e += 256) {
        int ls = e >> 5, j = e & 31;
        int s = t0 - 63 + ls;
        projL[ls*33 + j] = (s >= 0) ? proj[((long long)(b*T_ + s))*512 + h*32 + j] : 0.f;
    }
    for (int e = tid; e < 127*64; e += 256) {
        int ls = e >> 6;
        int s = t0 - 63 + ls;
        valL[e] = (s >= 0) ? valb[((long long)(b*T_ + s))*1024 + h*64 + (e & 63)]
                           : (unsigned short)0;
    }
    for (int e = tid; e < 64*16; e += 256) {
        int w_ = e >> 4, j = e & 15;
        posL[w_*17 + j] = posf[e];
    }
    __syncthreads();

    const int wid = tid >> 6, lane = tid & 63;
    const float db0 = db[0];
    const float ISQ2 = 0.70710678118654752f;

    for (int i = 0; i < 16; ++i) {
        int trel = wid*16 + i;              // t - t0
        int t = t0 + trel;
        int lt = trel + 63;                 // LDS row of position t
        int ls = trel + lane;               // LDS row of s = t-63+lane
        bool valid = (t - 63 + lane) >= 0;
        float bond = 0.f, dam = 0.f;
        #pragma unroll
        for (int j = 0; j < 16; ++j) {
            float zb = projL[ls*33 + j] - projL[lt*33 + j] + sfb[j] + posL[lane*17 + j];
            bond += 0.5f * zb * (1.f + erff(zb * ISQ2)) * bw[j];
            float zd = projL[ls*33 + 16 + j] - projL[lt*33 + 16 + j] + sfb[16 + j];
            dam += 0.5f * zd * (1.f + erff(zd * ISQ2)) * dw[j];
        }
        float damage = 1.f / (1.f + __expf(-(dam + db0)));
        float logit = bond - 10.f * damage;
        logit = valid ? logit : -INFINITY;
        float mx = logit;
        #pragma unroll
        for (int off = 32; off; off >>= 1) mx = fmaxf(mx, __shfl_xor(mx, off));
        float ex = valid ? __expf(logit - mx) : 0.f;
        float sm = ex;
        #pragma unroll
        for (int off = 32; off; off >>= 1) sm += __shfl_xor(sm, off);
        float wgt = ex / sm;
        // weighted sum over window: lane = d (HS=64)
        float acc = 0.f;
        #pragma unroll
        for (int w2 = 0; w2 < 64; ++w2) {
            float ww = __uint_as_float(
                __builtin_amdgcn_readlane(__float_as_uint(wgt), w2));
            acc += ww * bf2f(valL[(trel + w2)*64 + lane]);
        }
        attb[((long long)(b*T_ + t))*1024 + h*64 + lane] = f2bf(acc);
    }
}

extern "C" void kernel_launch(void* const* d_in, const int* in_sizes, int n_in,
                              void* d_out, int out_size, void* d_ws, size_t ws_size,
                              hipStream_t stream) {
    const float* x    = (const float*)d_in[0];
    const float* Wd   = (const float*)d_in[1];
    const float* Wv   = (const float*)d_in[2];
    const float* rel  = (const float*)d_in[3];
    const float* sfw  = (const float*)d_in[4];
    const float* sfb  = (const float*)d_in[5];
    const float* ppw  = (const float*)d_in[6];
    const float* bow  = (const float*)d_in[7];
    const float* dow  = (const float*)d_in[8];
    const float* dob  = (const float*)d_in[9];
    const float* cpw  = (const float*)d_in[10];
    float* out = (float*)d_out;

    char* w = (char*)d_ws;
    unsigned short* xb      = (unsigned short*)(w);                    //  8.4 MB
    unsigned short* wvalb   = (unsigned short*)(w + 8388608);          //  2.1 MB
    unsigned short* cprojb  = (unsigned short*)(w + 10485760);         //  2.1 MB
    unsigned short* wcombb  = (unsigned short*)(w + 12582912);         //  1.0 MB
    float*          posfeat = (float*)         (w + 13631488);         //  4 KB
    float*          proj    = (float*)         (w + 13635584);         //  8.4 MB
    unsigned short* valbuf  = (unsigned short*)(w + 22024192);         //  8.4 MB
    unsigned short* attb    = (unsigned short*)(w + 30412800);         //  8.4 MB
    // total ~38.8 MB

    cvt_kernel<<<6144, 256, 0, stream>>>(x, Wv, cpw, xb, wvalb, cprojb);
    wcomb_kernel<<<2048, 256, 0, stream>>>(Wd, sfw, wcombb);
    posfeat_kernel<<<4, 256, 0, stream>>>(rel, ppw, posfeat);
    // proj = x @ W_comb^T : (4096 x 512)
    gemm_bt<0><<<dim3(8, 64), 256, 0, stream>>>(xb, wcombb, proj, B_*T_, 512, C_);
    // val = x @ W_val^T : (4096 x 1024), bf16 out
    gemm_bt<1><<<dim3(16, 64), 256, 0, stream>>>(xb, wvalb, valbuf, B_*T_, C_, C_);
    attn_kernel<<<dim3(T_/64, NH_, B_), 256, 0, stream>>>(
        proj, valbuf, posfeat, sfb, bow, dow, dob, attb);
    // out = att @ c_proj^T : (4096 x 1024), fp32 out
    gemm_bt<0><<<dim3(16, 64), 256, 0, stream>>>(attb, cprojb, out, B_*T_, C_, C_);
}

// Round 2
// 248.357 us; speedup vs baseline: 1.2529x; 1.2529x over previous
//
#include <hip/hip_runtime.h>
#include <hip/hip_bf16.h>
#include <math.h>

#define B_ 2
#define T_ 2048
#define C_ 1024
#define NH_ 16
#define HS_ 64
#define BD_ 16
#define DELTA 64

typedef __attribute__((ext_vector_type(8))) short bf16x8_t;
typedef __attribute__((ext_vector_type(4))) float f32x4_t;

__device__ __forceinline__ unsigned short f2bf(float f) {
    unsigned u = __float_as_uint(f);
    u = u + 0x7fffu + ((u >> 16) & 1u);
    return (unsigned short)(u >> 16);
}
__device__ __forceinline__ float bf2f(unsigned short h) {
    return __uint_as_float(((unsigned)h) << 16);
}
// tanh-approx gelu: z * sigmoid(2*0.7978845608*(z + 0.044715 z^3))
// = z * rcp(1 + exp(z*(-1.5957691216 - 0.0713548163 z^2)))
__device__ __forceinline__ float gelu_t(float z) {
    float z2 = z * z;
    float m = z * fmaf(z2, -0.0713548163f, -1.5957691216f);
    return z * __builtin_amdgcn_rcpf(1.f + __expf(m));
}

// ---- prep: fp32 -> bf16 conversion for x, W_val, c_proj_w ----
__global__ __launch_bounds__(256) void cvt_kernel(
    const float* __restrict__ x, const float* __restrict__ wval,
    const float* __restrict__ cproj,
    unsigned short* __restrict__ xb, unsigned short* __restrict__ wvalb,
    unsigned short* __restrict__ cprojb)
{
    const long long NX = (long long)B_*T_*C_;
    const long long NW = (long long)C_*C_;
    long long e = ((long long)blockIdx.x * 256 + threadIdx.x) * 4;
    const float* src; unsigned short* dst; long long off;
    if (e < NX)            { src = x;     dst = xb;     off = e; }
    else if (e < NX + NW)  { src = wval;  dst = wvalb;  off = e - NX; }
    else                   { src = cproj; dst = cprojb; off = e - NX - NW; }
    float4 v = *(const float4*)(src + off);
    ushort4 o;
    o.x = f2bf(v.x); o.y = f2bf(v.y); o.z = f2bf(v.z); o.w = f2bf(v.w);
    *(ushort4*)(dst + off) = o;
}

// ---- W_comb[h*32+j, c] = sum_d sfw[j*16+d] * W_disp[(h*16+d)*1024 + c] ----
__global__ __launch_bounds__(256) void wcomb_kernel(
    const float* __restrict__ Wd, const float* __restrict__ sfw,
    unsigned short* __restrict__ wc)
{
    int idx = blockIdx.x * 256 + threadIdx.x;
    int c = idx & 1023, row = idx >> 10;
    int h = row >> 5, j = row & 31;
    float s = 0.f;
    #pragma unroll
    for (int d = 0; d < 16; ++d) s += sfw[j*16 + d] * Wd[(h*16 + d)*1024 + c];
    wc[idx] = f2bf(s);
}

// ---- pos_feat[w, j] = sum_d rel[w*16+d] * ppw[j*16+d] ----
__global__ __launch_bounds__(256) void posfeat_kernel(
    const float* __restrict__ rel, const float* __restrict__ ppw,
    float* __restrict__ pf)
{
    int idx = blockIdx.x * 256 + threadIdx.x;
    if (idx >= 64*16) return;
    int w_ = idx >> 4, j = idx & 15;
    float s = 0.f;
    #pragma unroll
    for (int d = 0; d < 16; ++d) s += rel[w_*16 + d] * ppw[j*16 + d];
    pf[idx] = s;
}

// ---- C[M,N] = A[M,K] @ Bw[N,K]^T, bf16 in, fp32 acc ----
template<int OUT_BF16>
__global__ __launch_bounds__(256) void gemm_bt(
    const unsigned short* __restrict__ A,
    const unsigned short* __restrict__ Bw,
    void* __restrict__ Cp, int M, int N, int K)
{
    __shared__ unsigned short As[64*40];
    __shared__ unsigned short Bs[64*40];
    const int tid = threadIdx.x;
    const int lane = tid & 63;
    const int wid = tid >> 6;
    const int waveM = wid >> 1, waveN = wid & 1;
    const int m0 = blockIdx.y * 64, n0 = blockIdx.x * 64;
    const int r = tid >> 2, cs = tid & 3;
    const int row16 = lane & 15, quad = lane >> 4;

    f32x4_t acc[2][2];
    #pragma unroll
    for (int i = 0; i < 2; ++i)
        #pragma unroll
        for (int j = 0; j < 2; ++j) { f32x4_t z = {0.f,0.f,0.f,0.f}; acc[i][j] = z; }

    for (int k0 = 0; k0 < K; k0 += 32) {
        uint4 av = *(const uint4*)(A  + (long long)(m0 + r) * K + k0 + cs*8);
        uint4 bv = *(const uint4*)(Bw + (long long)(n0 + r) * K + k0 + cs*8);
        __syncthreads();
        *(uint4*)(As + r*40 + cs*8) = av;
        *(uint4*)(Bs + r*40 + cs*8) = bv;
        __syncthreads();
        bf16x8_t af[2], bfv[2];
        #pragma unroll
        for (int mt = 0; mt < 2; ++mt)
            af[mt] = *(const bf16x8_t*)(As + (waveM*32 + mt*16 + row16)*40 + quad*8);
        #pragma unroll
        for (int nt = 0; nt < 2; ++nt)
            bfv[nt] = *(const bf16x8_t*)(Bs + (waveN*32 + nt*16 + row16)*40 + quad*8);
        #pragma unroll
        for (int mt = 0; mt < 2; ++mt)
            #pragma unroll
            for (int nt = 0; nt < 2; ++nt)
                acc[mt][nt] = __builtin_amdgcn_mfma_f32_16x16x32_bf16(
                    af[mt], bfv[nt], acc[mt][nt], 0, 0, 0);
    }
    #pragma unroll
    for (int mt = 0; mt < 2; ++mt)
        #pragma unroll
        for (int nt = 0; nt < 2; ++nt) {
            int col = n0 + waveN*32 + nt*16 + row16;
            #pragma unroll
            for (int rr = 0; rr < 4; ++rr) {
                int row = m0 + waveM*32 + mt*16 + quad*4 + rr;
                float v = acc[mt][nt][rr];
                if (OUT_BF16)
                    ((unsigned short*)Cp)[(long long)row * N + col] = f2bf(v);
                else
                    ((float*)Cp)[(long long)row * N + col] = v;
            }
        }
}

// ---- windowed attention, v2: cheap gelu + MFMA for the PV product ----
// One block per (b, h, 64 t's). 4 waves; lane = window pos w in stage 1/2.
__global__ __launch_bounds__(256) void attn_kernel(
    const unsigned short* __restrict__ projb,  // (B*T, 512) bf16
    const unsigned short* __restrict__ valb,   // (B*T, 1024) bf16
    const float* __restrict__ posf,            // (64,16)
    const float* __restrict__ sfb,             // (32,)
    const float* __restrict__ bw,              // (16,)
    const float* __restrict__ dw,              // (16,)
    const float* __restrict__ db,              // (1,)
    unsigned short* __restrict__ attb)         // (B*T, 1024) bf16
{
    // pitch 36 (b64-aligned, gcd(18,32)=2 -> only 4-way read aliasing)
    __shared__ __align__(16) unsigned short projL[127*36];  //  9144 B
    __shared__ __align__(16) unsigned short valLT[64*136];  // 17408 B (transposed [d][s])
    __shared__ __align__(16) unsigned short wgtA[64*136];   // 17408 B ([t][s_local])
    const int t0 = blockIdx.x * 64;
    const int h = blockIdx.y, b = blockIdx.z;
    const int tid = threadIdx.x;
    const int lane = tid & 63, wid = tid >> 6;

    // zero the padded weight tile (1088 uint4)
    for (int e = tid; e < 1088; e += 256) ((uint4*)wgtA)[e] = make_uint4(0,0,0,0);
    // stage proj rows [t0-63, t0+63]
    for (int e = tid; e < 127*32; e += 256) {
        int ls = e >> 5, j = e & 31;
        int s = t0 - 63 + ls;
        projL[ls*36 + j] = (s >= 0) ? projb[((long long)(b*T_ + s))*512 + h*32 + j]
                                    : (unsigned short)0;
    }
    // stage val transposed: valLT[d][s_local]
    for (int e = tid; e < 127*64; e += 256) {
        int ls = e >> 6, d = e & 63;
        int s = t0 - 63 + ls;
        valLT[d*136 + ls] = (s >= 0) ? valb[((long long)(b*T_ + s))*1024 + h*64 + d]
                                     : (unsigned short)0;
    }
    // per-lane constants (lane = w)
    float cbond[16];
    #pragma unroll
    for (int j = 0; j < 16; ++j) cbond[j] = sfb[j] + posf[lane*16 + j];
    const float db0 = db[0];
    __syncthreads();

    // stage 1+2: logits -> softmax -> bf16 weights into wgtA
    for (int i = 0; i < 16; ++i) {
        const int trel = wid*16 + i;
        const int lt = trel + 63;
        const int lsr = trel + lane;
        const bool valid = (t0 + trel - 63 + lane) >= 0;
        ushort4 sv[8], tv[8];
        #pragma unroll
        for (int k = 0; k < 8; ++k) {
            sv[k] = *(const ushort4*)(projL + lsr*36 + k*4);
            tv[k] = *(const ushort4*)(projL + lt*36  + k*4);
        }
        float bond = 0.f, dam = 0.f;
        #pragma unroll
        for (int k = 0; k < 4; ++k) {   // bond features j = 4k..4k+3
            float z0 = bf2f(sv[k].x) - bf2f(tv[k].x) + cbond[4*k+0];
            float z1 = bf2f(sv[k].y) - bf2f(tv[k].y) + cbond[4*k+1];
            float z2 = bf2f(sv[k].z) - bf2f(tv[k].z) + cbond[4*k+2];
            float z3 = bf2f(sv[k].w) - bf2f(tv[k].w) + cbond[4*k+3];
            bond += gelu_t(z0)*bw[4*k+0] + gelu_t(z1)*bw[4*k+1]
                  + gelu_t(z2)*bw[4*k+2] + gelu_t(z3)*bw[4*k+3];
        }
        #pragma unroll
        for (int k = 0; k < 4; ++k) {   // damage features j = 4k..4k+3
            float z0 = bf2f(sv[k+4].x) - bf2f(tv[k+4].x) + sfb[16 + 4*k+0];
            float z1 = bf2f(sv[k+4].y) - bf2f(tv[k+4].y) + sfb[16 + 4*k+1];
            float z2 = bf2f(sv[k+4].z) - bf2f(tv[k+4].z) + sfb[16 + 4*k+2];
            float z3 = bf2f(sv[k+4].w) - bf2f(tv[k+4].w) + sfb[16 + 4*k+3];
            dam += gelu_t(z0)*dw[4*k+0] + gelu_t(z1)*dw[4*k+1]
                 + gelu_t(z2)*dw[4*k+2] + gelu_t(z3)*dw[4*k+3];
        }
        float damage = __builtin_amdgcn_rcpf(1.f + __expf(-(dam + db0)));
        float logit = bond - 10.f * damage;
        logit = valid ? logit : -INFINITY;
        float mx = logit;
        #pragma unroll
        for (int off = 32; off; off >>= 1) mx = fmaxf(mx, __shfl_xor(mx, off));
        float ex = valid ? __expf(logit - mx) : 0.f;
        float sm = ex;
        #pragma unroll
        for (int off = 32; off; off >>= 1) sm += __shfl_xor(sm, off);
        float wgt = ex * __builtin_amdgcn_rcpf(sm);
        // W2[t][s_local]: s_local = trel + lane
        wgtA[trel*136 + trel + lane] = f2bf(wgt);
    }
    __syncthreads();

    // stage 3: out(64x64) = wgtA(64x128) @ val(128x64) via MFMA
    const int waveM = wid >> 1, waveN = wid & 1;
    const int row16 = lane & 15, quad = lane >> 4;
    f32x4_t acc[2][2];
    #pragma unroll
    for (int i = 0; i < 2; ++i)
        #pragma unroll
        for (int j = 0; j < 2; ++j) { f32x4_t z = {0.f,0.f,0.f,0.f}; acc[i][j] = z; }
    #pragma unroll
    for (int k0 = 0; k0 < 128; k0 += 32) {
        bf16x8_t af[2], bfv[2];
        #pragma unroll
        for (int mt = 0; mt < 2; ++mt)
            af[mt] = *(const bf16x8_t*)(wgtA + (waveM*32 + mt*16 + row16)*136 + k0 + quad*8);
        #pragma unroll
        for (int nt = 0; nt < 2; ++nt)
            bfv[nt] = *(const bf16x8_t*)(valLT + (waveN*32 + nt*16 + row16)*136 + k0 + quad*8);
        #pragma unroll
        for (int mt = 0; mt < 2; ++mt)
            #pragma unroll
            for (int nt = 0; nt < 2; ++nt)
                acc[mt][nt] = __builtin_amdgcn_mfma_f32_16x16x32_bf16(
                    af[mt], bfv[nt], acc[mt][nt], 0, 0, 0);
    }
    #pragma unroll
    for (int mt = 0; mt < 2; ++mt)
        #pragma unroll
        for (int nt = 0; nt < 2; ++nt) {
            int d = waveN*32 + nt*16 + row16;
            #pragma unroll
            for (int rr = 0; rr < 4; ++rr) {
                int t = t0 + waveM*32 + mt*16 + quad*4 + rr;
                attb[((long long)(b*T_ + t))*1024 + h*64 + d] = f2bf(acc[mt][nt][rr]);
            }
        }
}

extern "C" void kernel_launch(void* const* d_in, const int* in_sizes, int n_in,
                              void* d_out, int out_size, void* d_ws, size_t ws_size,
                              hipStream_t stream) {
    const float* x    = (const float*)d_in[0];
    const float* Wd   = (const float*)d_in[1];
    const float* Wv   = (const float*)d_in[2];
    const float* rel  = (const float*)d_in[3];
    const float* sfw  = (const float*)d_in[4];
    const float* sfb  = (const float*)d_in[5];
    const float* ppw  = (const float*)d_in[6];
    const float* bow  = (const float*)d_in[7];
    const float* dow  = (const float*)d_in[8];
    const float* dob  = (const float*)d_in[9];
    const float* cpw  = (const float*)d_in[10];
    float* out = (float*)d_out;

    char* w = (char*)d_ws;
    unsigned short* xb      = (unsigned short*)(w);
    unsigned short* wvalb   = (unsigned short*)(w + 8388608);
    unsigned short* cprojb  = (unsigned short*)(w + 10485760);
    unsigned short* wcombb  = (unsigned short*)(w + 12582912);
    float*          posfeat = (float*)         (w + 13631488);
    unsigned short* projb   = (unsigned short*)(w + 13635584);  // bf16 now (4.2 MB used)
    unsigned short* valbuf  = (unsigned short*)(w + 22024192);
    unsigned short* attb    = (unsigned short*)(w + 30412800);

    cvt_kernel<<<6144, 256, 0, stream>>>(x, Wv, cpw, xb, wvalb, cprojb);
    wcomb_kernel<<<2048, 256, 0, stream>>>(Wd, sfw, wcombb);
    posfeat_kernel<<<4, 256, 0, stream>>>(rel, ppw, posfeat);
    // proj = x @ W_comb^T : (4096 x 512), bf16 out
    gemm_bt<1><<<dim3(8, 64), 256, 0, stream>>>(xb, wcombb, projb, B_*T_, 512, C_);
    // val = x @ W_val^T : (4096 x 1024), bf16 out
    gemm_bt<1><<<dim3(16, 64), 256, 0, stream>>>(xb, wvalb, valbuf, B_*T_, C_, C_);
    attn_kernel<<<dim3(T_/64, NH_, B_), 256, 0, stream>>>(
        projb, valbuf, posfeat, sfb, bow, dow, dob, attb);
    // out = att @ c_proj^T : (4096 x 1024), fp32 out
    gemm_bt<0><<<dim3(16, 64), 256, 0, stream>>>(attb, cprojb, out, B_*T_, C_, C_);
}

// Round 3
// 227.639 us; speedup vs baseline: 1.3669x; 1.0910x over previous
//
#include <hip/hip_runtime.h>
#include <hip/hip_bf16.h>
#include <math.h>

#define B_ 2
#define T_ 2048
#define C_ 1024
#define NH_ 16
#define HS_ 64
#define BD_ 16
#define DELTA 64

typedef __attribute__((ext_vector_type(8))) short bf16x8_t;
typedef __attribute__((ext_vector_type(4))) float f32x4_t;
typedef __attribute__((address_space(1))) const unsigned int GUI;
typedef __attribute__((address_space(3))) unsigned int LUI;

__device__ __forceinline__ unsigned short f2bf(float f) {
    unsigned u = __float_as_uint(f);
    u = u + 0x7fffu + ((u >> 16) & 1u);
    return (unsigned short)(u >> 16);
}
__device__ __forceinline__ float bf2f(unsigned short h) {
    return __uint_as_float(((unsigned)h) << 16);
}
// tanh-approx gelu (max dev ~3e-4, fine vs 3.75e-2 threshold)
__device__ __forceinline__ float gelu_t(float z) {
    float z2 = z * z;
    float m = z * fmaf(z2, -0.0713548163f, -1.5957691216f);
    return z * __builtin_amdgcn_rcpf(1.f + __expf(m));
}
__device__ __forceinline__ void glds16(const unsigned short* g, unsigned short* l) {
    __builtin_amdgcn_global_load_lds((GUI*)g, (LUI*)l, 16, 0, 0);
}

// ---- prep: fp32 -> bf16 for x, W_val (into wcat+512K), c_proj_w ----
__global__ __launch_bounds__(256) void cvt_kernel(
    const float* __restrict__ x, const float* __restrict__ wval,
    const float* __restrict__ cproj,
    unsigned short* __restrict__ xb, unsigned short* __restrict__ wvalb,
    unsigned short* __restrict__ cprojb)
{
    const long long NX = (long long)B_*T_*C_;
    const long long NW = (long long)C_*C_;
    long long e = ((long long)blockIdx.x * 256 + threadIdx.x) * 4;
    const float* src; unsigned short* dst; long long off;
    if (e < NX)            { src = x;     dst = xb;     off = e; }
    else if (e < NX + NW)  { src = wval;  dst = wvalb;  off = e - NX; }
    else                   { src = cproj; dst = cprojb; off = e - NX - NW; }
    float4 v = *(const float4*)(src + off);
    ushort4 o;
    o.x = f2bf(v.x); o.y = f2bf(v.y); o.z = f2bf(v.z); o.w = f2bf(v.w);
    *(ushort4*)(dst + off) = o;
}

// ---- W_comb[h*32+j, c] = sum_d sfw[j*16+d] * W_disp[(h*16+d)*1024 + c] ----
__global__ __launch_bounds__(256) void wcomb_kernel(
    const float* __restrict__ Wd, const float* __restrict__ sfw,
    unsigned short* __restrict__ wc)
{
    int idx = blockIdx.x * 256 + threadIdx.x;
    int c = idx & 1023, row = idx >> 10;
    int h = row >> 5, j = row & 31;
    float s = 0.f;
    #pragma unroll
    for (int d = 0; d < 16; ++d) s += sfw[j*16 + d] * Wd[(h*16 + d)*1024 + c];
    wc[idx] = f2bf(s);
}

// ---- pos_feat[w, j] = sum_d rel[w*16+d] * ppw[j*16+d] ----
__global__ __launch_bounds__(256) void posfeat_kernel(
    const float* __restrict__ rel, const float* __restrict__ ppw,
    float* __restrict__ pf)
{
    int idx = blockIdx.x * 256 + threadIdx.x;
    if (idx >= 64*16) return;
    int w_ = idx >> 4, j = idx & 15;
    float s = 0.f;
    #pragma unroll
    for (int d = 0; d < 16; ++d) s += rel[w_*16 + d] * ppw[j*16 + d];
    pf[idx] = s;
}

// ---- 128x128-tile GEMM (m97-style): C[M,N] = A[M,K] @ Bw[N,K]^T ----
// bf16 in, fp32 acc; global_load_lds width-16 staging; unpadded 32-ushort rows.
template<int OUT_BF16>
__global__ __launch_bounds__(256) void gemm128(
    const unsigned short* __restrict__ A,
    const unsigned short* __restrict__ Bw,
    void* __restrict__ Cp, int M, int N, int K)
{
    __shared__ unsigned short As[128*32];   // 8 KB, no padding (glds constraint)
    __shared__ unsigned short Bs[128*32];
    const int tid = threadIdx.x;
    const int lane = tid & 63;
    const int wid = tid >> 6;
    const int waveM = wid >> 1, waveN = wid & 1;
    const int m0 = blockIdx.y * 128, n0 = blockIdx.x * 128;
    const int row16 = lane & 15, quad = lane >> 4;
    // staging chunk mapping: chunk c (16B) -> row c>>2, col (c&3)*8
    const int c0 = tid, c1 = tid + 256;
    const int r0 = c0 >> 2, cc0 = (c0 & 3) * 8;
    const int r1 = c1 >> 2, cc1 = (c1 & 3) * 8;
    unsigned short* ldsA0 = As + (wid*64)*8;          // wave-uniform bases
    unsigned short* ldsA1 = As + (256 + wid*64)*8;
    unsigned short* ldsB0 = Bs + (wid*64)*8;
    unsigned short* ldsB1 = Bs + (256 + wid*64)*8;

    f32x4_t acc[4][4];
    #pragma unroll
    for (int i = 0; i < 4; ++i)
        #pragma unroll
        for (int j = 0; j < 4; ++j) { f32x4_t z = {0.f,0.f,0.f,0.f}; acc[i][j] = z; }

    for (int k0 = 0; k0 < K; k0 += 32) {
        glds16(A  + (long long)(m0 + r0) * K + k0 + cc0, ldsA0);
        glds16(A  + (long long)(m0 + r1) * K + k0 + cc1, ldsA1);
        glds16(Bw + (long long)(n0 + r0) * K + k0 + cc0, ldsB0);
        glds16(Bw + (long long)(n0 + r1) * K + k0 + cc1, ldsB1);
        __syncthreads();   // drains vmcnt: staged data visible
        bf16x8_t af[4], bfv[4];
        #pragma unroll
        for (int mt = 0; mt < 4; ++mt)
            af[mt] = *(const bf16x8_t*)(As + (waveM*64 + mt*16 + row16)*32 + quad*8);
        #pragma unroll
        for (int nt = 0; nt < 4; ++nt)
            bfv[nt] = *(const bf16x8_t*)(Bs + (waveN*64 + nt*16 + row16)*32 + quad*8);
        #pragma unroll
        for (int mt = 0; mt < 4; ++mt)
            #pragma unroll
            for (int nt = 0; nt < 4; ++nt)
                acc[mt][nt] = __builtin_amdgcn_mfma_f32_16x16x32_bf16(
                    af[mt], bfv[nt], acc[mt][nt], 0, 0, 0);
        __syncthreads();   // all waves done reading before next overwrite
    }
    #pragma unroll
    for (int mt = 0; mt < 4; ++mt)
        #pragma unroll
        for (int nt = 0; nt < 4; ++nt) {
            int col = n0 + waveN*64 + nt*16 + row16;
            #pragma unroll
            for (int rr = 0; rr < 4; ++rr) {
                int row = m0 + waveM*64 + mt*16 + quad*4 + rr;
                float v = acc[mt][nt][rr];
                if (OUT_BF16)
                    ((unsigned short*)Cp)[(long long)row * N + col] = f2bf(v);
                else
                    ((float*)Cp)[(long long)row * N + col] = v;
            }
        }
}

// ---- windowed attention v3: conflict-free LDS layouts ----
// ccat: (B*T, 1536) bf16 = [proj(512) | val(1024)]
__global__ __launch_bounds__(256) void attn_kernel(
    const unsigned short* __restrict__ ccat,
    const float* __restrict__ posf,            // (64,16)
    const float* __restrict__ sfb,             // (32,)
    const float* __restrict__ bw,              // (16,)
    const float* __restrict__ dw,              // (16,)
    const float* __restrict__ db,              // (1,)
    unsigned short* __restrict__ attb)         // (B*T, 1024) bf16
{
    __shared__ __align__(16) unsigned short projL[127*34];  //  8636 B, 17-dword pitch (odd)
    __shared__ __align__(16) unsigned short valL[127*66];   // 16764 B, [s][d], 33-dword pitch
    __shared__ __align__(16) unsigned short wgtA[64*136];   // 17408 B, [t][s_local]
    const int t0 = blockIdx.x * 64;
    const int h = blockIdx.y, b = blockIdx.z;
    const int tid = threadIdx.x;
    const int lane = tid & 63, wid = tid >> 6;

    // zero weight tile (64 rows x 17 uint4)
    for (int e = tid; e < 1088; e += 256) ((uint4*)wgtA)[e] = make_uint4(0,0,0,0);
    // stage proj rows [t0-63, t0+63]: ushort2 per thread (conflict-free, coalesced)
    for (int e = tid; e < 127*16; e += 256) {
        int ls = e >> 4, j2 = e & 15;
        int s = t0 - 63 + ls;
        ushort2 v = make_ushort2(0, 0);
        if (s >= 0) v = *(const ushort2*)(ccat + (long long)(b*T_ + s)*1536 + h*32 + j2*2);
        *(ushort2*)(projL + ls*34 + j2*2) = v;
    }
    // stage val rows [s][d] un-transposed: ushort4 per thread
    for (int e = tid; e < 127*16; e += 256) {
        int ls = e >> 4, d4 = e & 15;
        int s = t0 - 63 + ls;
        ushort4 v = make_ushort4(0, 0, 0, 0);
        if (s >= 0) v = *(const ushort4*)(ccat + (long long)(b*T_ + s)*1536 + 512 + h*64 + d4*4);
        *(ushort4*)(valL + ls*66 + d4*4) = v;
    }
    float cbond[16];
    #pragma unroll
    for (int j = 0; j < 16; ++j) cbond[j] = sfb[j] + posf[lane*16 + j];
    const float db0 = db[0];
    __syncthreads();

    // stage 1+2: logits -> softmax -> bf16 weights (lane = window pos)
    for (int i = 0; i < 16; ++i) {
        const int trel = wid*16 + i;
        const int lt = trel + 63;
        const int lsr = trel + lane;
        const bool valid = (t0 + trel - 63 + lane) >= 0;
        ushort2 sv[16], tv[16];
        #pragma unroll
        for (int k = 0; k < 16; ++k) {
            sv[k] = *(const ushort2*)(projL + lsr*34 + k*2);
            tv[k] = *(const ushort2*)(projL + lt*34  + k*2);
        }
        float bond = 0.f, dam = 0.f;
        #pragma unroll
        for (int k = 0; k < 8; ++k) {          // bond j = 2k, 2k+1
            float z0 = bf2f(sv[k].x) - bf2f(tv[k].x) + cbond[2*k];
            float z1 = bf2f(sv[k].y) - bf2f(tv[k].y) + cbond[2*k+1];
            bond += gelu_t(z0)*bw[2*k] + gelu_t(z1)*bw[2*k+1];
        }
        #pragma unroll
        for (int k = 0; k < 8; ++k) {          // damage j = 2k, 2k+1
            float z0 = bf2f(sv[k+8].x) - bf2f(tv[k+8].x) + sfb[16 + 2*k];
            float z1 = bf2f(sv[k+8].y) - bf2f(tv[k+8].y) + sfb[16 + 2*k+1];
            dam += gelu_t(z0)*dw[2*k] + gelu_t(z1)*dw[2*k+1];
        }
        float damage = __builtin_amdgcn_rcpf(1.f + __expf(-(dam + db0)));
        float logit = bond - 10.f * damage;
        logit = valid ? logit : -INFINITY;
        float mx = logit;
        #pragma unroll
        for (int off = 32; off; off >>= 1) mx = fmaxf(mx, __shfl_xor(mx, off));
        float ex = valid ? __expf(logit - mx) : 0.f;
        float sm = ex;
        #pragma unroll
        for (int off = 32; off; off >>= 1) sm += __shfl_xor(sm, off);
        float wgt = ex * __builtin_amdgcn_rcpf(sm);
        wgtA[trel*136 + trel + lane] = f2bf(wgt);   // consecutive lanes: stride-1, free
    }
    __syncthreads();

    // stage 3: out(64t x 64d) = wgtA(64x128) @ valL(128x64) via MFMA
    const int waveM = wid >> 1, waveN = wid & 1;
    const int row16 = lane & 15, quad = lane >> 4;
    f32x4_t acc[2][2];
    #pragma unroll
    for (int i = 0; i < 2; ++i)
        #pragma unroll
        for (int j = 0; j < 2; ++j) { f32x4_t z = {0.f,0.f,0.f,0.f}; acc[i][j] = z; }
    #pragma unroll
    for (int k0 = 0; k0 < 128; k0 += 32) {
        bf16x8_t af[2], bfv[2];
        #pragma unroll
        for (int mt = 0; mt < 2; ++mt)
            af[mt] = *(const bf16x8_t*)(wgtA + (waveM*32 + mt*16 + row16)*136 + k0 + quad*8);
        #pragma unroll
        for (int nt = 0; nt < 2; ++nt) {       // B-frag: u16 gather from [s][d] (conflict-free)
            int d = waveN*32 + nt*16 + row16;
            bf16x8_t bv;
            #pragma unroll
            for (int j = 0; j < 8; ++j)
                bv[j] = (short)valL[(k0 + quad*8 + j)*66 + d];
            bfv[nt] = bv;
        }
        #pragma unroll
        for (int mt = 0; mt < 2; ++mt)
            #pragma unroll
            for (int nt = 0; nt < 2; ++nt)
                acc[mt][nt] = __builtin_amdgcn_mfma_f32_16x16x32_bf16(
                    af[mt], bfv[nt], acc[mt][nt], 0, 0, 0);
    }
    #pragma unroll
    for (int mt = 0; mt < 2; ++mt)
        #pragma unroll
        for (int nt = 0; nt < 2; ++nt) {
            int d = waveN*32 + nt*16 + row16;
            #pragma unroll
            for (int rr = 0; rr < 4; ++rr) {
                int t = t0 + waveM*32 + mt*16 + quad*4 + rr;
                attb[((long long)(b*T_ + t))*1024 + h*64 + d] = f2bf(acc[mt][nt][rr]);
            }
        }
}

extern "C" void kernel_launch(void* const* d_in, const int* in_sizes, int n_in,
                              void* d_out, int out_size, void* d_ws, size_t ws_size,
                              hipStream_t stream) {
    const float* x    = (const float*)d_in[0];
    const float* Wd   = (const float*)d_in[1];
    const float* Wv   = (const float*)d_in[2];
    const float* rel  = (const float*)d_in[3];
    const float* sfw  = (const float*)d_in[4];
    const float* sfb  = (const float*)d_in[5];
    const float* ppw  = (const float*)d_in[6];
    const float* bow  = (const float*)d_in[7];
    const float* dow  = (const float*)d_in[8];
    const float* dob  = (const float*)d_in[9];
    const float* cpw  = (const float*)d_in[10];
    float* out = (float*)d_out;

    char* w = (char*)d_ws;
    unsigned short* xb      = (unsigned short*)(w);                 // 8,388,608 B
    unsigned short* wcat    = (unsigned short*)(w + 8388608);       // 3,145,728 B (512 wcomb + 1024 wval rows)
    unsigned short* cprojb  = (unsigned short*)(w + 11534336);      // 2,097,152 B
    float*          posfeat = (float*)         (w + 13631488);      //     4,096 B
    unsigned short* ccat    = (unsigned short*)(w + 13635584);      // 12,582,912 B (4096 x 1536)
    unsigned short* attb    = (unsigned short*)(w + 26218496);      // 8,388,608 B

    cvt_kernel<<<6144, 256, 0, stream>>>(x, Wv, cpw, xb, wcat + 512*1024, cprojb);
    wcomb_kernel<<<2048, 256, 0, stream>>>(Wd, sfw, wcat);
    posfeat_kernel<<<4, 256, 0, stream>>>(rel, ppw, posfeat);
    // ccat = x @ [W_comb; W_val]^T : (4096 x 1536), bf16
    gemm128<1><<<dim3(12, 32), 256, 0, stream>>>(xb, wcat, ccat, B_*T_, 1536, C_);
    attn_kernel<<<dim3(T_/64, NH_, B_), 256, 0, stream>>>(
        ccat, posfeat, sfb, bow, dow, dob, attb);
    // out = att @ c_proj^T : (4096 x 1024), fp32
    gemm128<0><<<dim3(8, 32), 256, 0, stream>>>(attb, cprojb, out, B_*T_, C_, C_);
}

// Round 5
// 212.322 us; speedup vs baseline: 1.4655x; 1.0721x over previous
//
#include <hip/hip_runtime.h>
#include <hip/hip_bf16.h>
#include <math.h>

#define B_ 2
#define T_ 2048
#define C_ 1024
#define NH_ 16
#define HS_ 64
#define BD_ 16
#define DELTA 64

typedef __attribute__((ext_vector_type(8))) short bf16x8_t;
typedef __attribute__((ext_vector_type(4))) float f32x4_t;
typedef __attribute__((address_space(1))) const unsigned int GUI;
typedef __attribute__((address_space(3))) unsigned int LUI;

__device__ __forceinline__ unsigned short f2bf(float f) {
    unsigned u = __float_as_uint(f);
    u = u + 0x7fffu + ((u >> 16) & 1u);
    return (unsigned short)(u >> 16);
}
__device__ __forceinline__ float bf2f(unsigned short h) {
    return __uint_as_float(((unsigned)h) << 16);
}
__device__ __forceinline__ float bflo(unsigned u) {
    return __uint_as_float(u << 16);
}
__device__ __forceinline__ float bfhi(unsigned u) {
    return __uint_as_float(u & 0xffff0000u);
}
// tanh-approx gelu (max dev ~3e-4, fine vs 3.75e-2 threshold)
__device__ __forceinline__ float gelu_t(float z) {
    float z2 = z * z;
    float m = z * fmaf(z2, -0.0713548163f, -1.5957691216f);
    return z * __builtin_amdgcn_rcpf(1.f + __expf(m));
}
__device__ __forceinline__ void glds16(const unsigned short* g, unsigned short* l) {
    __builtin_amdgcn_global_load_lds((GUI*)g, (LUI*)l, 16, 0, 0);
}

// ---- prep: fp32 -> bf16 for x, W_val, c_proj_w ----
__global__ __launch_bounds__(256) void cvt_kernel(
    const float* __restrict__ x, const float* __restrict__ wval,
    const float* __restrict__ cproj,
    unsigned short* __restrict__ xb, unsigned short* __restrict__ wvalb,
    unsigned short* __restrict__ cprojb)
{
    const long long NX = (long long)B_*T_*C_;
    const long long NW = (long long)C_*C_;
    long long e = ((long long)blockIdx.x * 256 + threadIdx.x) * 4;
    const float* src; unsigned short* dst; long long off;
    if (e < NX)            { src = x;     dst = xb;     off = e; }
    else if (e < NX + NW)  { src = wval;  dst = wvalb;  off = e - NX; }
    else                   { src = cproj; dst = cprojb; off = e - NX - NW; }
    float4 v = *(const float4*)(src + off);
    ushort4 o;
    o.x = f2bf(v.x); o.y = f2bf(v.y); o.z = f2bf(v.z); o.w = f2bf(v.w);
    *(ushort4*)(dst + off) = o;
}

// ---- W_comb + pos_feat fused ----
__global__ __launch_bounds__(256) void wcomb_kernel(
    const float* __restrict__ Wd, const float* __restrict__ sfw,
    const float* __restrict__ rel, const float* __restrict__ ppw,
    unsigned short* __restrict__ wc, float* __restrict__ pf)
{
    if (blockIdx.x == 2048) {
        for (int e = threadIdx.x; e < 64*16; e += 256) {
            int w_ = e >> 4, j = e & 15;
            float s = 0.f;
            #pragma unroll
            for (int d = 0; d < 16; ++d) s += rel[w_*16 + d] * ppw[j*16 + d];
            pf[e] = s;
        }
        return;
    }
    int idx = blockIdx.x * 256 + threadIdx.x;
    int c = idx & 1023, row = idx >> 10;
    int h = row >> 5, j = row & 31;
    float s = 0.f;
    #pragma unroll
    for (int d = 0; d < 16; ++d) s += sfw[j*16 + d] * Wd[(h*16 + d)*1024 + c];
    wc[idx] = f2bf(s);
}

// ---- 64x128-tile GEMM: C[M,N] = A[M,K] @ Bw[N,K]^T, bf16 in, fp32 acc ----
template<int OUT_BF16>
__global__ __launch_bounds__(256) void gemm64x128(
    const unsigned short* __restrict__ A,
    const unsigned short* __restrict__ Bw,
    void* __restrict__ Cp, int M, int N, int K)
{
    __shared__ unsigned short As[64*32];    //  4 KB
    __shared__ unsigned short Bs[128*32];   //  8 KB
    const int tid = threadIdx.x;
    const int lane = tid & 63;
    const int wid = tid >> 6;
    const int waveM = wid >> 1, waveN = wid & 1;
    const int m0 = blockIdx.y * 64, n0 = blockIdx.x * 128;
    const int row16 = lane & 15, quad = lane >> 4;
    const int rA = tid >> 2,          ccA = (tid & 3) * 8;
    const int rB0 = tid >> 2,         ccB0 = ccA;
    const int rB1 = (tid + 256) >> 2, ccB1 = ccA;
    unsigned short* ldsA  = As + wid*512;
    unsigned short* ldsB0 = Bs + wid*512;
    unsigned short* ldsB1 = Bs + 2048 + wid*512;

    f32x4_t acc[2][4];
    #pragma unroll
    for (int i = 0; i < 2; ++i)
        #pragma unroll
        for (int j = 0; j < 4; ++j) { f32x4_t z = {0.f,0.f,0.f,0.f}; acc[i][j] = z; }

    for (int k0 = 0; k0 < K; k0 += 32) {
        glds16(A  + (long long)(m0 + rA)  * K + k0 + ccA,  ldsA);
        glds16(Bw + (long long)(n0 + rB0) * K + k0 + ccB0, ldsB0);
        glds16(Bw + (long long)(n0 + rB1) * K + k0 + ccB1, ldsB1);
        __syncthreads();
        bf16x8_t af[2], bfv[4];
        #pragma unroll
        for (int mt = 0; mt < 2; ++mt)
            af[mt] = *(const bf16x8_t*)(As + (waveM*32 + mt*16 + row16)*32 + quad*8);
        #pragma unroll
        for (int nt = 0; nt < 4; ++nt)
            bfv[nt] = *(const bf16x8_t*)(Bs + (waveN*64 + nt*16 + row16)*32 + quad*8);
        #pragma unroll
        for (int mt = 0; mt < 2; ++mt)
            #pragma unroll
            for (int nt = 0; nt < 4; ++nt)
                acc[mt][nt] = __builtin_amdgcn_mfma_f32_16x16x32_bf16(
                    af[mt], bfv[nt], acc[mt][nt], 0, 0, 0);
        __syncthreads();
    }
    #pragma unroll
    for (int mt = 0; mt < 2; ++mt)
        #pragma unroll
        for (int nt = 0; nt < 4; ++nt) {
            int col = n0 + waveN*64 + nt*16 + row16;
            #pragma unroll
            for (int rr = 0; rr < 4; ++rr) {
                int row = m0 + waveM*32 + mt*16 + quad*4 + rr;
                float v = acc[mt][nt][rr];
                if (OUT_BF16)
                    ((unsigned short*)Cp)[(long long)row * N + col] = f2bf(v);
                else
                    ((float*)Cp)[(long long)row * N + col] = v;
            }
        }
}

// ---- windowed attention v5: v4 + valL sized 128 rows, row 127 zeroed ----
// (fixes 0 x uninitialized-LDS NaN from stage-3 k=127 reads)
__global__ __launch_bounds__(256) void attn_kernel(
    const unsigned short* __restrict__ ccat,   // (B*T, 1536) bf16 = [proj|val]
    const float* __restrict__ posf,            // (64,16)
    const float* __restrict__ sfb,             // (32,)
    const float* __restrict__ bw,              // (16,)
    const float* __restrict__ dw,              // (16,)
    const float* __restrict__ db,              // (1,)
    unsigned short* __restrict__ attb)         // (B*T, 1024) bf16
{
    __shared__ __align__(16) unsigned short valL[128*66];   // 16896 B, [s][d], row 127 = zeros
    __shared__ __align__(16) unsigned short wgtA[64*136];   // 17408 B, [t][s_local]
    const int t0 = blockIdx.x * 64;
    const int h = blockIdx.y, b = blockIdx.z;
    const int tid = threadIdx.x;
    const int lane = tid & 63, wid = tid >> 6;

    for (int e = tid; e < 1088; e += 256) ((uint4*)wgtA)[e] = make_uint4(0,0,0,0);
    // stage val rows [s][d]; ls in 0..127; ls==127 (and s<0) -> zeros
    for (int e = tid; e < 128*16; e += 256) {
        int ls = e >> 4, d4 = e & 15;
        int s = t0 - 63 + ls;
        ushort4 v = make_ushort4(0, 0, 0, 0);
        if (s >= 0 && ls < 127)
            v = *(const ushort4*)(ccat + (long long)(b*T_ + s)*1536 + 512 + h*64 + d4*4);
        *(ushort4*)(valL + ls*66 + d4*4) = v;
    }
    float cbond[16];
    #pragma unroll
    for (int j = 0; j < 16; ++j) cbond[j] = sfb[j] + posf[lane*16 + j];
    float cdam[16];
    #pragma unroll
    for (int j = 0; j < 16; ++j) cdam[j] = sfb[16 + j];
    const float db0 = db[0];
    __syncthreads();

    // stage 1+2: logits -> softmax -> bf16 weights (lane = window pos w)
    for (int i = 0; i < 16; ++i) {
        const int trel = wid*16 + i;
        const int t = t0 + trel;
        const int s = t - 63 + lane;
        const bool valid = s >= 0;
        const unsigned short* srow = ccat + (long long)(b*T_ + (valid ? s : 0))*1536 + h*32;
        const unsigned short* trow = ccat + (long long)(b*T_ + t)*1536 + h*32;
        uint4 sv[2], tv[2], sd[2], td[2];
        sv[0] = ((const uint4*)srow)[0];  sv[1] = ((const uint4*)srow)[1];
        sd[0] = ((const uint4*)srow)[2];  sd[1] = ((const uint4*)srow)[3];
        tv[0] = ((const uint4*)trow)[0];  tv[1] = ((const uint4*)trow)[1];
        td[0] = ((const uint4*)trow)[2];  td[1] = ((const uint4*)trow)[3];
        float bond = 0.f, dam = 0.f;
        #pragma unroll
        for (int k = 0; k < 2; ++k) {
            const unsigned* su = (const unsigned*)&sv[k];
            const unsigned* tu = (const unsigned*)&tv[k];
            #pragma unroll
            for (int q = 0; q < 4; ++q) {
                int j = k*8 + q*2;
                float z0 = bflo(su[q]) - bflo(tu[q]) + cbond[j];
                float z1 = bfhi(su[q]) - bfhi(tu[q]) + cbond[j+1];
                bond += gelu_t(z0)*bw[j] + gelu_t(z1)*bw[j+1];
            }
        }
        #pragma unroll
        for (int k = 0; k < 2; ++k) {
            const unsigned* su = (const unsigned*)&sd[k];
            const unsigned* tu = (const unsigned*)&td[k];
            #pragma unroll
            for (int q = 0; q < 4; ++q) {
                int j = k*8 + q*2;
                float z0 = bflo(su[q]) - bflo(tu[q]) + cdam[j];
                float z1 = bfhi(su[q]) - bfhi(tu[q]) + cdam[j+1];
                dam += gelu_t(z0)*dw[j] + gelu_t(z1)*dw[j+1];
            }
        }
        float damage = __builtin_amdgcn_rcpf(1.f + __expf(-(dam + db0)));
        float logit = bond - 10.f * damage;
        logit = valid ? logit : -INFINITY;
        float mx = logit;
        #pragma unroll
        for (int off = 32; off; off >>= 1) mx = fmaxf(mx, __shfl_xor(mx, off));
        float ex = valid ? __expf(logit - mx) : 0.f;
        float sm = ex;
        #pragma unroll
        for (int off = 32; off; off >>= 1) sm += __shfl_xor(sm, off);
        float wgt = ex * __builtin_amdgcn_rcpf(sm);
        wgtA[trel*136 + trel + lane] = f2bf(wgt);
    }
    __syncthreads();

    // stage 3: out(64t x 64d) = wgtA(64x128) @ valL(128x64) via MFMA, banded.
    const int waveM = wid >> 1, waveN = wid & 1;
    const int row16 = lane & 15, quad = lane >> 4;
    f32x4_t acc[2][2];
    #pragma unroll
    for (int i = 0; i < 2; ++i)
        #pragma unroll
        for (int j = 0; j < 2; ++j) { f32x4_t z = {0.f,0.f,0.f,0.f}; acc[i][j] = z; }
    #pragma unroll
    for (int kk = 0; kk < 3; ++kk) {
        const int k0 = waveM*32 + kk*32;
        bf16x8_t af[2], bfv[2];
        #pragma unroll
        for (int mt = 0; mt < 2; ++mt)
            af[mt] = *(const bf16x8_t*)(wgtA + (waveM*32 + mt*16 + row16)*136 + k0 + quad*8);
        #pragma unroll
        for (int nt = 0; nt < 2; ++nt) {
            int d = waveN*32 + nt*16 + row16;
            bf16x8_t bv;
            #pragma unroll
            for (int j = 0; j < 8; ++j)
                bv[j] = (short)valL[(k0 + quad*8 + j)*66 + d];
            bfv[nt] = bv;
        }
        #pragma unroll
        for (int mt = 0; mt < 2; ++mt)
            #pragma unroll
            for (int nt = 0; nt < 2; ++nt)
                acc[mt][nt] = __builtin_amdgcn_mfma_f32_16x16x32_bf16(
                    af[mt], bfv[nt], acc[mt][nt], 0, 0, 0);
    }
    #pragma unroll
    for (int mt = 0; mt < 2; ++mt)
        #pragma unroll
        for (int nt = 0; nt < 2; ++nt) {
            int d = waveN*32 + nt*16 + row16;
            #pragma unroll
            for (int rr = 0; rr < 4; ++rr) {
                int t = t0 + waveM*32 + mt*16 + quad*4 + rr;
                attb[((long long)(b*T_ + t))*1024 + h*64 + d] = f2bf(acc[mt][nt][rr]);
            }
        }
}

extern "C" void kernel_launch(void* const* d_in, const int* in_sizes, int n_in,
                              void* d_out, int out_size, void* d_ws, size_t ws_size,
                              hipStream_t stream) {
    const float* x    = (const float*)d_in[0];
    const float* Wd   = (const float*)d_in[1];
    const float* Wv   = (const float*)d_in[2];
    const float* rel  = (const float*)d_in[3];
    const float* sfw  = (const float*)d_in[4];
    const float* sfb  = (const float*)d_in[5];
    const float* ppw  = (const float*)d_in[6];
    const float* bow  = (const float*)d_in[7];
    const float* dow  = (const float*)d_in[8];
    const float* dob  = (const float*)d_in[9];
    const float* cpw  = (const float*)d_in[10];
    float* out = (float*)d_out;

    char* w = (char*)d_ws;
    unsigned short* xb      = (unsigned short*)(w);                 // 8,388,608 B
    unsigned short* wcat    = (unsigned short*)(w + 8388608);       // 3,145,728 B
    unsigned short* cprojb  = (unsigned short*)(w + 11534336);      // 2,097,152 B
    float*          posfeat = (float*)         (w + 13631488);      //     4,096 B
    unsigned short* ccat    = (unsigned short*)(w + 13635584);      // 12,582,912 B (4096 x 1536)
    unsigned short* attb    = (unsigned short*)(w + 26218496);      // 8,388,608 B

    cvt_kernel<<<6144, 256, 0, stream>>>(x, Wv, cpw, xb, wcat + 512*1024, cprojb);
    wcomb_kernel<<<2049, 256, 0, stream>>>(Wd, sfw, rel, ppw, wcat, posfeat);
    // ccat = x @ [W_comb; W_val]^T : (4096 x 1536), bf16  -- 768 blocks
    gemm64x128<1><<<dim3(12, 64), 256, 0, stream>>>(xb, wcat, ccat, B_*T_, 1536, C_);
    attn_kernel<<<dim3(T_/64, NH_, B_), 256, 0, stream>>>(
        ccat, posfeat, sfb, bow, dow, dob, attb);
    // out = att @ c_proj^T : (4096 x 1024), fp32  -- 512 blocks
    gemm64x128<0><<<dim3(8, 64), 256, 0, stream>>>(attb, cprojb, out, B_*T_, C_, C_);
}